// Round 1
// baseline (64.618 us; speedup 1.0000x reference)
//
#include <hip/hip_runtime.h>

#define IN_F 8192
#define OUT_F 8192
#define BATCH 32
#define HALFG ((OUT_F / 2) * (IN_F / 128))  // 262144 groups in the hi-nibble half

typedef __bf16 bf16x8 __attribute__((ext_vector_type(8)));
typedef __bf16 bf16x4 __attribute__((ext_vector_type(4)));
typedef float f32x4 __attribute__((ext_vector_type(4)));

union ABFrag { bf16x8 v; uint2 h[2]; };

// Convert x fp32 -> bf16 once per launch (saves per-K-step cvt + halves x traffic)
__global__ __launch_bounds__(256) void xcvt_kernel(const float4* __restrict__ x,
                                                   bf16x4* __restrict__ xb) {
    int i = blockIdx.x * 256 + threadIdx.x;  // 65536 float4s
    float4 v = x[i];
    bf16x4 o;
    o[0] = (__bf16)v.x; o[1] = (__bf16)v.y; o[2] = (__bf16)v.z; o[3] = (__bf16)v.w;
    xb[i] = o;
}

__global__ __launch_bounds__(256) void bias_init_kernel(const float4* __restrict__ bias,
                                                        float4* __restrict__ out) {
    int i = blockIdx.x * 256 + threadIdx.x;  // 65536 float4s over [32][8192]
    out[i] = bias[i & 2047];
}

// Block: 4 waves, each wave owns 16 pair-rows (o, o+4096) x all 32 batches.
// Per K-step of 32: 2 dwordx4 packed loads/lane -> both nibbles -> 2 B-frags,
// 4 MFMA (2 batch-tiles x {hi,lo}).
template <int KSPLIT, bool FAST>
__global__ __launch_bounds__(256) void qgemm_kernel(
    const float* __restrict__ xf, const __bf16* __restrict__ xb,
    const int* __restrict__ packed, const float* __restrict__ scale,
    const float* __restrict__ zero, float* __restrict__ outp) {
    constexpr int KCHUNK = IN_F / KSPLIT;
    const int w = threadIdx.x >> 6;      // wave 0..3
    const int lane = threadIdx.x & 63;
    const int r = lane & 15;             // MFMA n (out-row offset) / m (batch offset)
    const int q = lane >> 4;             // 0..3 -> k sub-offset q*4
    const int nb = blockIdx.x;           // 0..63 N-block
    const int ks = blockIdx.y;           // K-split
    const int pr = nb * 64 + w * 16 + r; // packed row (= hi out-row), < 4096
    const int kbase = ks * KCHUNK;

    f32x4 acc[2][2] = {{{0.f, 0.f, 0.f, 0.f}, {0.f, 0.f, 0.f, 0.f}},
                       {{0.f, 0.f, 0.f, 0.f}, {0.f, 0.f, 0.f, 0.f}}};

    const int* pk = packed + (size_t)pr * IN_F;

    for (int kg = 0; kg < KCHUNK / 128; ++kg) {
        const int gcol = (kbase >> 7) + kg;       // group column 0..63
        const int ghi = pr * 64 + gcol;
        const float s_hi = scale[ghi];
        const float z_hi = zero[ghi];
        const float s_lo = scale[ghi + HALFG];
        const float z_lo = zero[ghi + HALFG];
        const float zs_hi = -z_hi * s_hi;
        const float zs_lo = -z_lo * s_lo;
#pragma unroll
        for (int ki = 0; ki < 4; ++ki) {
            const int k0 = kbase + kg * 128 + ki * 32 + q * 4;
            // B operand: packed ints (hi+lo nibbles -> two fragments)
            int4 p0 = *(const int4*)(pk + k0);
            int4 p1 = *(const int4*)(pk + k0 + 16);
            // A operand: x rows r and 16+r
            ABFrag a0, a1;
            if (FAST) {
                a0.h[0] = *(const uint2*)(xb + (size_t)r * IN_F + k0);
                a0.h[1] = *(const uint2*)(xb + (size_t)r * IN_F + k0 + 16);
                a1.h[0] = *(const uint2*)(xb + (size_t)(16 + r) * IN_F + k0);
                a1.h[1] = *(const uint2*)(xb + (size_t)(16 + r) * IN_F + k0 + 16);
            } else {
                float4 x00 = *(const float4*)(xf + (size_t)r * IN_F + k0);
                float4 x01 = *(const float4*)(xf + (size_t)r * IN_F + k0 + 16);
                float4 x10 = *(const float4*)(xf + (size_t)(16 + r) * IN_F + k0);
                float4 x11 = *(const float4*)(xf + (size_t)(16 + r) * IN_F + k0 + 16);
                a0.v[0] = (__bf16)x00.x; a0.v[1] = (__bf16)x00.y;
                a0.v[2] = (__bf16)x00.z; a0.v[3] = (__bf16)x00.w;
                a0.v[4] = (__bf16)x01.x; a0.v[5] = (__bf16)x01.y;
                a0.v[6] = (__bf16)x01.z; a0.v[7] = (__bf16)x01.w;
                a1.v[0] = (__bf16)x10.x; a1.v[1] = (__bf16)x10.y;
                a1.v[2] = (__bf16)x10.z; a1.v[3] = (__bf16)x10.w;
                a1.v[4] = (__bf16)x11.x; a1.v[5] = (__bf16)x11.y;
                a1.v[6] = (__bf16)x11.z; a1.v[7] = (__bf16)x11.w;
            }
            int pp[8] = {p0.x, p0.y, p0.z, p0.w, p1.x, p1.y, p1.z, p1.w};
            bf16x8 bhi, blo;
#pragma unroll
            for (int j = 0; j < 8; ++j) {
                bhi[j] = (__bf16)fmaf((float)((pp[j] >> 4) & 15), s_hi, zs_hi);
                blo[j] = (__bf16)fmaf((float)(pp[j] & 15), s_lo, zs_lo);
            }
            acc[0][0] = __builtin_amdgcn_mfma_f32_16x16x32_bf16(a0.v, bhi, acc[0][0], 0, 0, 0);
            acc[1][0] = __builtin_amdgcn_mfma_f32_16x16x32_bf16(a1.v, bhi, acc[1][0], 0, 0, 0);
            acc[0][1] = __builtin_amdgcn_mfma_f32_16x16x32_bf16(a0.v, blo, acc[0][1], 0, 0, 0);
            acc[1][1] = __builtin_amdgcn_mfma_f32_16x16x32_bf16(a1.v, blo, acc[1][1], 0, 0, 0);
        }
    }

    // Epilogue. C layout (m89-verified): col = lane&15 -> out row o; row = q*4+j -> batch.
#pragma unroll
    for (int bt = 0; bt < 2; ++bt) {
#pragma unroll
        for (int hl = 0; hl < 2; ++hl) {
            const int o = nb * 64 + w * 16 + r + hl * (OUT_F / 2);
#pragma unroll
            for (int j = 0; j < 4; ++j) {
                const int b = bt * 16 + q * 4 + j;
                if (FAST) {
                    outp[(size_t)ks * (BATCH * OUT_F) + (size_t)b * OUT_F + o] = acc[bt][hl][j];
                } else {
                    atomicAdd(&outp[(size_t)b * OUT_F + o], acc[bt][hl][j]);
                }
            }
        }
    }
}

template <int KSPLIT>
__global__ __launch_bounds__(256) void reduce_kernel(const float4* __restrict__ part,
                                                     const float4* __restrict__ bias,
                                                     float4* __restrict__ out) {
    int i = blockIdx.x * 256 + threadIdx.x;  // 65536 float4s
    float4 s = bias[i & 2047];
#pragma unroll
    for (int k = 0; k < KSPLIT; ++k) {
        float4 p = part[(size_t)k * (BATCH * OUT_F / 4) + i];
        s.x += p.x; s.y += p.y; s.z += p.z; s.w += p.w;
    }
    out[i] = s;
}

extern "C" void kernel_launch(void* const* d_in, const int* in_sizes, int n_in,
                              void* d_out, int out_size, void* d_ws, size_t ws_size,
                              hipStream_t stream) {
    (void)in_sizes; (void)n_in; (void)out_size;
    const float* x = (const float*)d_in[0];
    const int* packed = (const int*)d_in[1];
    const float* scale = (const float*)d_in[2];
    const float* zero = (const float*)d_in[3];
    const float* bias = (const float*)d_in[4];
    float* out = (float*)d_out;

    constexpr int KSPLIT = 8;
    const size_t part_bytes = (size_t)KSPLIT * BATCH * OUT_F * sizeof(float);
    const size_t need = part_bytes + (size_t)BATCH * IN_F * sizeof(__bf16);

    if (ws_size >= need) {
        float* part = (float*)d_ws;
        __bf16* xb = (__bf16*)((char*)d_ws + part_bytes);
        xcvt_kernel<<<256, 256, 0, stream>>>((const float4*)x, (bf16x4*)xb);
        qgemm_kernel<KSPLIT, true><<<dim3(OUT_F / 2 / 64, KSPLIT), 256, 0, stream>>>(
            nullptr, xb, packed, scale, zero, part);
        reduce_kernel<KSPLIT><<<256, 256, 0, stream>>>((const float4*)part,
                                                       (const float4*)bias, (float4*)out);
    } else {
        // Fallback when workspace is too small: bias-init + fp32-x + atomic split-K.
        bias_init_kernel<<<256, 256, 0, stream>>>((const float4*)bias, (float4*)out);
        qgemm_kernel<KSPLIT, false><<<dim3(OUT_F / 2 / 64, KSPLIT), 256, 0, stream>>>(
            x, nullptr, packed, scale, zero, out);
    }
}

// Round 2
// 39.379 us; speedup vs baseline: 1.6409x; 1.6409x over previous
//
#include <hip/hip_runtime.h>

#define IN_F 8192
#define OUT_F 8192
#define BATCH 32
#define HALFG ((OUT_F / 2) * (IN_F / 128))  // 262144 groups in the hi-nibble half
#define NFRAG_HALF 16384                    // 256 k-steps * 64 lanes per batch-half

typedef __bf16 bf16x8 __attribute__((ext_vector_type(8)));
typedef __bf16 bf16x4 __attribute__((ext_vector_type(4)));
typedef float f32x4 __attribute__((ext_vector_type(4)));

union ABFrag { bf16x8 v; uint2 h[2]; int4 i4; };

// Convert x fp32 -> bf16 AND repack into MFMA A-fragment order:
// frag index = half*16384 + k32*64 + q*16 + r  (lane = q*16+r)
// frag contents j=0..3: x[half*16+r][k32*32+q*4+j]; j=4..7: ... +16+j
__global__ __launch_bounds__(256) void xcvt_kernel(const float* __restrict__ x,
                                                   bf16x8* __restrict__ xc) {
    int t = blockIdx.x * 256 + threadIdx.x;  // 32768 frags
    int r = t & 15;
    int q = (t >> 4) & 3;
    int k32 = (t >> 6) & 255;
    int half = t >> 14;
    int b = half * 16 + r;
    int kb = k32 * 32 + q * 4;
    float4 x0 = *(const float4*)(x + (size_t)b * IN_F + kb);
    float4 x1 = *(const float4*)(x + (size_t)b * IN_F + kb + 16);
    bf16x8 o;
    o[0] = (__bf16)x0.x; o[1] = (__bf16)x0.y; o[2] = (__bf16)x0.z; o[3] = (__bf16)x0.w;
    o[4] = (__bf16)x1.x; o[5] = (__bf16)x1.y; o[6] = (__bf16)x1.z; o[7] = (__bf16)x1.w;
    xc[t] = o;
}

__global__ __launch_bounds__(256) void bias_init_kernel(const float4* __restrict__ bias,
                                                        float4* __restrict__ out) {
    int i = blockIdx.x * 256 + threadIdx.x;
    out[i] = bias[i & 2047];
}

// Block: 4 waves, each wave owns 16 pair-rows (o, o+4096) x all 32 batches.
template <int KSPLIT, bool FAST>
__global__ __launch_bounds__(256, 4) void qgemm_kernel(
    const float* __restrict__ xf, const bf16x8* __restrict__ xc,
    const int* __restrict__ packed, const float* __restrict__ scale,
    const float* __restrict__ zero, float* __restrict__ outp) {
    constexpr int KCHUNK = IN_F / KSPLIT;      // 512
    constexpr int NKG = KCHUNK / 128;          // 4 groups
    const int w = threadIdx.x >> 6;
    const int lane = threadIdx.x & 63;
    const int r = lane & 15;
    const int q = lane >> 4;
    const int nb = blockIdx.x;                 // 0..63
    const int ks = blockIdx.y;                 // 0..KSPLIT-1
    const int pr = nb * 64 + w * 16 + r;       // packed row < 4096
    const int kbase = ks * KCHUNK;

    f32x4 acc[2][2] = {{{0.f, 0.f, 0.f, 0.f}, {0.f, 0.f, 0.f, 0.f}},
                       {{0.f, 0.f, 0.f, 0.f}, {0.f, 0.f, 0.f, 0.f}}};

    const int* pk = packed + (size_t)pr * IN_F;

    // Hoisted per-row group params: NKG=4 consecutive groups -> one float4 each.
    const int ghi = pr * 64 + (kbase >> 7);
    float4 sh = *(const float4*)(scale + ghi);
    float4 zh = *(const float4*)(zero + ghi);
    float4 sl = *(const float4*)(scale + ghi + HALFG);
    float4 zl = *(const float4*)(zero + ghi + HALFG);
    float4 zsh, zsl;
    zsh.x = -zh.x * sh.x; zsh.y = -zh.y * sh.y; zsh.z = -zh.z * sh.z; zsh.w = -zh.w * sh.w;
    zsl.x = -zl.x * sl.x; zsl.y = -zl.y * sl.y; zsl.z = -zl.z * sl.z; zsl.w = -zl.w * sl.w;
    const float sh_a[4] = {sh.x, sh.y, sh.z, sh.w};
    const float zsh_a[4] = {zsh.x, zsh.y, zsh.z, zsh.w};
    const float sl_a[4] = {sl.x, sl.y, sl.z, sl.w};
    const float zsl_a[4] = {zsl.x, zsl.y, zsl.z, zsl.w};

#pragma unroll
    for (int kg = 0; kg < NKG; ++kg) {
        const float s_hi = sh_a[kg], zs_hi = zsh_a[kg];
        const float s_lo = sl_a[kg], zs_lo = zsl_a[kg];
#pragma unroll
        for (int ki = 0; ki < 4; ++ki) {
            const int k32g = ks * (KCHUNK / 32) + kg * 4 + ki;  // global k-step
            const int k0 = kbase + kg * 128 + ki * 32 + q * 4;
            int4 p0 = *(const int4*)(pk + k0);
            int4 p1 = *(const int4*)(pk + k0 + 16);
            ABFrag a0, a1;
            if (FAST) {
                // fully-coalesced fragment loads (one dwordx4 per half)
                a0.i4 = *(const int4*)(xc + (size_t)k32g * 64 + lane);
                a1.i4 = *(const int4*)(xc + (size_t)NFRAG_HALF + (size_t)k32g * 64 + lane);
            } else {
                float4 x00 = *(const float4*)(xf + (size_t)r * IN_F + k0);
                float4 x01 = *(const float4*)(xf + (size_t)r * IN_F + k0 + 16);
                float4 x10 = *(const float4*)(xf + (size_t)(16 + r) * IN_F + k0);
                float4 x11 = *(const float4*)(xf + (size_t)(16 + r) * IN_F + k0 + 16);
                a0.v[0] = (__bf16)x00.x; a0.v[1] = (__bf16)x00.y;
                a0.v[2] = (__bf16)x00.z; a0.v[3] = (__bf16)x00.w;
                a0.v[4] = (__bf16)x01.x; a0.v[5] = (__bf16)x01.y;
                a0.v[6] = (__bf16)x01.z; a0.v[7] = (__bf16)x01.w;
                a1.v[0] = (__bf16)x10.x; a1.v[1] = (__bf16)x10.y;
                a1.v[2] = (__bf16)x10.z; a1.v[3] = (__bf16)x10.w;
                a1.v[4] = (__bf16)x11.x; a1.v[5] = (__bf16)x11.y;
                a1.v[6] = (__bf16)x11.z; a1.v[7] = (__bf16)x11.w;
            }
            int pp[8] = {p0.x, p0.y, p0.z, p0.w, p1.x, p1.y, p1.z, p1.w};
            bf16x8 bhi, blo;
#pragma unroll
            for (int j = 0; j < 8; ++j) {
                // pp[j] in [0,256): >>4 needs no mask
                bhi[j] = (__bf16)fmaf((float)(pp[j] >> 4), s_hi, zs_hi);
                blo[j] = (__bf16)fmaf((float)(pp[j] & 15), s_lo, zs_lo);
            }
            acc[0][0] = __builtin_amdgcn_mfma_f32_16x16x32_bf16(a0.v, bhi, acc[0][0], 0, 0, 0);
            acc[1][0] = __builtin_amdgcn_mfma_f32_16x16x32_bf16(a1.v, bhi, acc[1][0], 0, 0, 0);
            acc[0][1] = __builtin_amdgcn_mfma_f32_16x16x32_bf16(a0.v, blo, acc[0][1], 0, 0, 0);
            acc[1][1] = __builtin_amdgcn_mfma_f32_16x16x32_bf16(a1.v, blo, acc[1][1], 0, 0, 0);
        }
    }

    // C layout: col = lane&15 -> out row offset; row = q*4+j -> batch.
#pragma unroll
    for (int bt = 0; bt < 2; ++bt) {
#pragma unroll
        for (int hl = 0; hl < 2; ++hl) {
            const int o = nb * 64 + w * 16 + r + hl * (OUT_F / 2);
#pragma unroll
            for (int j = 0; j < 4; ++j) {
                const int b = bt * 16 + q * 4 + j;
                if (FAST) {
                    outp[(size_t)ks * (BATCH * OUT_F) + (size_t)b * OUT_F + o] = acc[bt][hl][j];
                } else {
                    atomicAdd(&outp[(size_t)b * OUT_F + o], acc[bt][hl][j]);
                }
            }
        }
    }
}

template <int KSPLIT>
__global__ __launch_bounds__(256) void reduce_kernel(const float4* __restrict__ part,
                                                     const float4* __restrict__ bias,
                                                     float4* __restrict__ out) {
    int i = blockIdx.x * 256 + threadIdx.x;  // 65536 float4s
    float4 s = bias[i & 2047];
#pragma unroll
    for (int k = 0; k < KSPLIT; ++k) {
        float4 p = part[(size_t)k * (BATCH * OUT_F / 4) + i];
        s.x += p.x; s.y += p.y; s.z += p.z; s.w += p.w;
    }
    out[i] = s;
}

extern "C" void kernel_launch(void* const* d_in, const int* in_sizes, int n_in,
                              void* d_out, int out_size, void* d_ws, size_t ws_size,
                              hipStream_t stream) {
    (void)in_sizes; (void)n_in; (void)out_size;
    const float* x = (const float*)d_in[0];
    const int* packed = (const int*)d_in[1];
    const float* scale = (const float*)d_in[2];
    const float* zero = (const float*)d_in[3];
    const float* bias = (const float*)d_in[4];
    float* out = (float*)d_out;

    constexpr int KSPLIT = 16;
    const size_t part_bytes = (size_t)KSPLIT * BATCH * OUT_F * sizeof(float);
    const size_t xc_bytes = (size_t)2 * NFRAG_HALF * 16;
    const size_t need = part_bytes + xc_bytes;

    if (ws_size >= need) {
        float* part = (float*)d_ws;
        bf16x8* xc = (bf16x8*)((char*)d_ws + part_bytes);
        xcvt_kernel<<<128, 256, 0, stream>>>(x, xc);
        qgemm_kernel<KSPLIT, true><<<dim3(OUT_F / 2 / 64, KSPLIT), 256, 0, stream>>>(
            nullptr, xc, packed, scale, zero, part);
        reduce_kernel<KSPLIT><<<256, 256, 0, stream>>>((const float4*)part,
                                                       (const float4*)bias, (float4*)out);
    } else {
        bias_init_kernel<<<256, 256, 0, stream>>>((const float4*)bias, (float4*)out);
        qgemm_kernel<KSPLIT, false><<<dim3(OUT_F / 2 / 64, KSPLIT), 256, 0, stream>>>(
            x, nullptr, packed, scale, zero, out);
    }
}